// Round 3
// baseline (599.280 us; speedup 1.0000x reference)
//
#include <hip/hip_runtime.h>
#include <hip/hip_bf16.h>

// GAT self-attention: Wh = h@W; out = softmax(leaky_relu(Wh@Wh^T)) @ Wh
// N=8192, IN_F=256, OUT_F=128. adj unused.
//
// Round 3 = Round 1 (known-passing) with ONE structural change:
//   flash kernel loads K / V^T MFMA fragments DIRECTLY from global
//   (L2-resident, 4 MiB total) instead of LDS staging -> no __syncthreads
//   in the loop at all. NSPLIT 4->8 for occupancy (1024 blocks, 4/CU).
// Everything else (wh_kernel incl. transposed store, softmax shfl chains,
// f16 P round-trip through per-wave LDS, epilogue, combine) is R1 verbatim.

#define SEQ   8192
#define DIM   128
#define IN_F  256
#define BM    64
#define BN    64
#define NSPLIT 8
#define JITER ((SEQ / NSPLIT) / BN)   // 16

typedef __attribute__((ext_vector_type(8))) _Float16 f16x8;
typedef __attribute__((ext_vector_type(4))) _Float16 f16x4;
typedef __attribute__((ext_vector_type(4))) float   floatx4;

// ---------------------------------------------------------------------------
// Kernel 1: Wh = h @ W (fp32 accum), emit Wh (f16 row-major) and Wh^T (f16).
// R1 verbatim. 1024 blocks x 256.
// ---------------------------------------------------------------------------
__global__ __launch_bounds__(256) void wh_kernel(
    const float* __restrict__ h, const float* __restrict__ W,
    _Float16* __restrict__ Wh16, _Float16* __restrict__ WhT16) {
  int tid = threadIdx.x;
  int cg  = tid & 31;         // column group: 4 fp32 cols
  int rl  = tid >> 5;         // 0..7
  int row = blockIdx.x * 8 + rl;
  const float4* W4 = (const float4*)W;          // [256][32] of float4
  const float4* h4 = (const float4*)(h + (size_t)row * IN_F);
  float4 acc = make_float4(0.f, 0.f, 0.f, 0.f);
#pragma unroll 8
  for (int k4 = 0; k4 < IN_F / 4; k4++) {
    float4 hv = h4[k4];
    float4 w0 = W4[(k4 * 4 + 0) * 32 + cg];
    float4 w1 = W4[(k4 * 4 + 1) * 32 + cg];
    float4 w2 = W4[(k4 * 4 + 2) * 32 + cg];
    float4 w3 = W4[(k4 * 4 + 3) * 32 + cg];
    acc.x += hv.x * w0.x + hv.y * w1.x + hv.z * w2.x + hv.w * w3.x;
    acc.y += hv.x * w0.y + hv.y * w1.y + hv.z * w2.y + hv.w * w3.y;
    acc.z += hv.x * w0.z + hv.y * w1.z + hv.z * w2.z + hv.w * w3.z;
    acc.w += hv.x * w0.w + hv.y * w1.w + hv.z * w2.w + hv.w * w3.w;
  }
  f16x4 r;
  r[0] = (_Float16)acc.x; r[1] = (_Float16)acc.y;
  r[2] = (_Float16)acc.z; r[3] = (_Float16)acc.w;
  *(f16x4*)&Wh16[(size_t)row * DIM + cg * 4] = r;
#pragma unroll
  for (int j = 0; j < 4; j++)
    WhT16[(size_t)(cg * 4 + j) * SEQ + row] = r[j];
}

// ---------------------------------------------------------------------------
// Kernel 2: flash attention, barrier-free. grid (128, NSPLIT), block 256.
// Wave owns 16 Q rows. K/V^T fragments direct from global (L2-resident).
// LDS: only the per-wave P transpose buffer (4 x 16 x 72 halves = 9216 B).
// ---------------------------------------------------------------------------
__global__ __launch_bounds__(256) void flash_kernel(
    const _Float16* __restrict__ Wh16, const _Float16* __restrict__ WhT16,
    float* __restrict__ Opart, float* __restrict__ mpart,
    float* __restrict__ lpart) {
  __shared__ _Float16 Psh[4 * 16 * 72];     // 9216 B

  const int tid  = threadIdx.x;
  const int lane = tid & 63;
  const int wave = tid >> 6;
  const int n16  = lane & 15;
  const int quad = lane >> 4;

  const int qbase  = blockIdx.x * BM + wave * 16;
  const int jbase0 = blockIdx.y * (SEQ / NSPLIT);

  // Q A-fragments, resident: A[m=lane&15][k=quad*8+j+32c]
  f16x8 qf[4];
#pragma unroll
  for (int c = 0; c < 4; c++)
    qf[c] = *(const f16x8*)&Wh16[(size_t)(qbase + n16) * DIM + c * 32 + quad * 8];

  floatx4 o[8];
#pragma unroll
  for (int ct = 0; ct < 8; ct++) o[ct] = (floatx4){0.f, 0.f, 0.f, 0.f};
  float m_run[4], l_run[4];
#pragma unroll
  for (int e = 0; e < 4; e++) { m_run[e] = -1e30f; l_run[e] = 0.f; }

  for (int it = 0; it < JITER; it++) {
    const int jbase = jbase0 + it * BN;

    // ---- S = Q K^T : K B-frags direct from global
    floatx4 s[4];
#pragma unroll
    for (int t = 0; t < 4; t++) {
      s[t] = (floatx4){0.f, 0.f, 0.f, 0.f};
#pragma unroll
      for (int c = 0; c < 4; c++) {
        f16x8 kf = *(const f16x8*)&Wh16[(size_t)(jbase + t * 16 + n16) * DIM +
                                        c * 32 + quad * 8];
        s[t] = __builtin_amdgcn_mfma_f32_16x16x32_f16(qf[c], kf, s[t], 0, 0, 0);
      }
    }
    // ---- leaky_relu(0.2)
#pragma unroll
    for (int t = 0; t < 4; t++)
#pragma unroll
      for (int e = 0; e < 4; e++) {
        float v = s[t][e];
        s[t][e] = v > 0.f ? v : 0.2f * v;
      }
    // ---- online softmax (C-layout): row r = quad*4+e across 16 lanes of quad
    float alpha[4];
#pragma unroll
    for (int e = 0; e < 4; e++) {
      float v = fmaxf(fmaxf(s[0][e], s[1][e]), fmaxf(s[2][e], s[3][e]));
      v = fmaxf(v, __shfl_xor(v, 1, 64));
      v = fmaxf(v, __shfl_xor(v, 2, 64));
      v = fmaxf(v, __shfl_xor(v, 4, 64));
      v = fmaxf(v, __shfl_xor(v, 8, 64));
      float mnew = fmaxf(m_run[e], v);
      alpha[e] = __expf(m_run[e] - mnew);
      m_run[e] = mnew;
    }
    float rs[4] = {0.f, 0.f, 0.f, 0.f};
#pragma unroll
    for (int t = 0; t < 4; t++)
#pragma unroll
      for (int e = 0; e < 4; e++) {
        float p = __expf(s[t][e] - m_run[e]);
        s[t][e] = p;
        rs[e] += p;
      }
#pragma unroll
    for (int e = 0; e < 4; e++) {
      float v = rs[e];
      v += __shfl_xor(v, 1, 64);
      v += __shfl_xor(v, 2, 64);
      v += __shfl_xor(v, 4, 64);
      v += __shfl_xor(v, 8, 64);
      l_run[e] = alpha[e] * l_run[e] + v;
    }
#pragma unroll
    for (int ct = 0; ct < 8; ct++)
#pragma unroll
      for (int e = 0; e < 4; e++) o[ct][e] *= alpha[e];

    // ---- P: C-layout -> A-layout via per-wave LDS region (intra-wave only)
    _Float16* Pw = Psh + wave * 1152;       // 16 rows x 72 halves
#pragma unroll
    for (int t = 0; t < 4; t++)
#pragma unroll
      for (int e = 0; e < 4; e++)
        Pw[(quad * 4 + e) * 72 + t * 16 + n16] = (_Float16)s[t][e];
    asm volatile("s_waitcnt lgkmcnt(0)" ::: "memory");
    f16x8 pa[2];
#pragma unroll
    for (int c = 0; c < 2; c++)
      pa[c] = *(const f16x8*)&Pw[n16 * 72 + c * 32 + quad * 8];

    // ---- O += P V : V^T B-frags direct from global
#pragma unroll
    for (int ct = 0; ct < 8; ct++)
#pragma unroll
      for (int c = 0; c < 2; c++) {
        f16x8 vf = *(const f16x8*)&WhT16[(size_t)(ct * 16 + n16) * SEQ + jbase +
                                         c * 32 + quad * 8];
        o[ct] = __builtin_amdgcn_mfma_f32_16x16x32_f16(pa[c], vf, o[ct], 0, 0, 0);
      }
  }

  // ---- write unnormalized partials for this key-split (R1 verbatim)
  const int sp = blockIdx.y;
  float* Op = Opart + (size_t)sp * SEQ * DIM;
#pragma unroll
  for (int ct = 0; ct < 8; ct++)
#pragma unroll
    for (int e = 0; e < 4; e++) {
      int row = qbase + quad * 4 + e;
      Op[(size_t)row * DIM + ct * 16 + n16] = o[ct][e];
    }
  if (n16 == 0) {
#pragma unroll
    for (int e = 0; e < 4; e++) {
      int row = qbase + quad * 4 + e;
      mpart[sp * SEQ + row] = m_run[e];
      lpart[sp * SEQ + row] = l_run[e];
    }
  }
}

// ---------------------------------------------------------------------------
// Kernel 3: log-sum-exp combine of NSPLIT partials -> out fp32 (R1 verbatim)
// ---------------------------------------------------------------------------
__global__ __launch_bounds__(256) void combine_kernel(
    const float* __restrict__ Opart, const float* __restrict__ mpart,
    const float* __restrict__ lpart, float* __restrict__ out) {
  int idx = blockIdx.x * 256 + threadIdx.x;   // 0 .. 8192*128-1
  int row = idx >> 7;
  float M = -1e30f;
#pragma unroll
  for (int p = 0; p < NSPLIT; p++) M = fmaxf(M, mpart[p * SEQ + row]);
  float num = 0.f, den = 0.f;
#pragma unroll
  for (int p = 0; p < NSPLIT; p++) {
    float e = __expf(mpart[p * SEQ + row] - M);
    den += e * lpart[p * SEQ + row];
    num += e * Opart[(size_t)p * SEQ * DIM + idx];
  }
  out[idx] = num / den;
}

// ---------------------------------------------------------------------------
extern "C" void kernel_launch(void* const* d_in, const int* in_sizes, int n_in,
                              void* d_out, int out_size, void* d_ws,
                              size_t ws_size, hipStream_t stream) {
  const float* h = (const float*)d_in[0];
  // d_in[1] = adj (unused by the reference math)
  const float* W = (const float*)d_in[2];
  float* out = (float*)d_out;

  char* ws = (char*)d_ws;
  _Float16* Wh16  = (_Float16*)ws;                                   // 2 MiB
  _Float16* WhT16 = (_Float16*)(ws + (size_t)2 * 1024 * 1024);       // 2 MiB
  float* Opart = (float*)(ws + (size_t)4 * 1024 * 1024);             // 32 MiB
  float* mpart = (float*)(ws + (size_t)36 * 1024 * 1024);            // 256 KiB
  float* lpart = (float*)(ws + (size_t)36 * 1024 * 1024 + 256 * 1024);

  wh_kernel<<<SEQ / 8, 256, 0, stream>>>(h, W, Wh16, WhT16);
  flash_kernel<<<dim3(SEQ / BM, NSPLIT), 256, 0, stream>>>(Wh16, WhT16,
                                                           Opart, mpart, lpart);
  combine_kernel<<<(SEQ * DIM) / 256, 256, 0, stream>>>(Opart, mpart, lpart, out);
}

// Round 4
// 476.093 us; speedup vs baseline: 1.2587x; 1.2587x over previous
//
#include <hip/hip_runtime.h>
#include <hip/hip_bf16.h>

// GAT self-attention: Wh = h@W; out = softmax(leaky_relu(Wh@Wh^T)) @ Wh
// N=8192, IN_F=256, OUT_F=128. adj unused.
//
// Round 4: back to LDS-staged flash (R1 shape) with two upgrades:
//  (a) staging via __builtin_amdgcn_global_load_lds width=16 in FRAGMENT
//      ORDER: each MFMA fragment = one 1 KB LDS chunk laid out exactly as
//      lane i -> base + i*16, so ds_read_b128 frag reads are linear and
//      conflict-free, and staging needs no VGPR round-trip.
//  (b) wave owns 32 Q rows (2 row-sets): every K/V fragment read feeds 2
//      MFMAs; block tile 128 rows. Grid (64 qtiles x NSPLIT=8) = 512 blocks.
// Softmax, P C->A LDS round-trip, epilogue, wh/combine: R1-verbatim.

#define SEQ   8192
#define DIM   128
#define IN_F  256
#define BN    64
#define QTILE 128
#define NSPLIT 8
#define JITER ((SEQ / NSPLIT) / BN)   // 16

typedef __attribute__((ext_vector_type(8))) _Float16 f16x8;
typedef __attribute__((ext_vector_type(4))) _Float16 f16x4;
typedef __attribute__((ext_vector_type(4))) float   floatx4;

__device__ __forceinline__ void load_lds16(const void* g, void* l) {
  __builtin_amdgcn_global_load_lds(
      (const __attribute__((address_space(1))) unsigned int*)g,
      (__attribute__((address_space(3))) unsigned int*)l, 16, 0, 0);
}

// ---------------------------------------------------------------------------
// Kernel 1: Wh = h @ W (fp32 accum), emit Wh (f16 row-major) and Wh^T (f16).
// R1 verbatim. 1024 blocks x 256.
// ---------------------------------------------------------------------------
__global__ __launch_bounds__(256) void wh_kernel(
    const float* __restrict__ h, const float* __restrict__ W,
    _Float16* __restrict__ Wh16, _Float16* __restrict__ WhT16) {
  int tid = threadIdx.x;
  int cg  = tid & 31;
  int rl  = tid >> 5;
  int row = blockIdx.x * 8 + rl;
  const float4* W4 = (const float4*)W;
  const float4* h4 = (const float4*)(h + (size_t)row * IN_F);
  float4 acc = make_float4(0.f, 0.f, 0.f, 0.f);
#pragma unroll 8
  for (int k4 = 0; k4 < IN_F / 4; k4++) {
    float4 hv = h4[k4];
    float4 w0 = W4[(k4 * 4 + 0) * 32 + cg];
    float4 w1 = W4[(k4 * 4 + 1) * 32 + cg];
    float4 w2 = W4[(k4 * 4 + 2) * 32 + cg];
    float4 w3 = W4[(k4 * 4 + 3) * 32 + cg];
    acc.x += hv.x * w0.x + hv.y * w1.x + hv.z * w2.x + hv.w * w3.x;
    acc.y += hv.x * w0.y + hv.y * w1.y + hv.z * w2.y + hv.w * w3.y;
    acc.z += hv.x * w0.z + hv.y * w1.z + hv.z * w2.z + hv.w * w3.z;
    acc.w += hv.x * w0.w + hv.y * w1.w + hv.z * w2.w + hv.w * w3.w;
  }
  f16x4 r;
  r[0] = (_Float16)acc.x; r[1] = (_Float16)acc.y;
  r[2] = (_Float16)acc.z; r[3] = (_Float16)acc.w;
  *(f16x4*)&Wh16[(size_t)row * DIM + cg * 4] = r;
#pragma unroll
  for (int j = 0; j < 4; j++)
    WhT16[(size_t)(cg * 4 + j) * SEQ + row] = r[j];
}

// ---------------------------------------------------------------------------
// Kernel 2: flash attention, LDS-staged in fragment order.
// grid (SEQ/QTILE=64, NSPLIT=8), block 256 = 4 waves; wave owns 32 Q rows.
// LDS: Kbuf 16 chunks x 1KB, Vbuf 16 chunks x 1KB, Psh 4x2x(16x72) halves.
// ---------------------------------------------------------------------------
__global__ __launch_bounds__(256) void flash_kernel(
    const _Float16* __restrict__ Wh16, const _Float16* __restrict__ WhT16,
    float* __restrict__ Opart, float* __restrict__ mpart,
    float* __restrict__ lpart) {
  __shared__ _Float16 Kbuf[16 * 512];       // 16 KiB
  __shared__ _Float16 Vbuf[16 * 512];       // 16 KiB
  __shared__ _Float16 Psh[4 * 2 * 16 * 72]; // 18 KiB

  const int tid  = threadIdx.x;
  const int lane = tid & 63;
  const int wave = tid >> 6;
  const int n16  = lane & 15;
  const int quad = lane >> 4;

  const int qbase  = blockIdx.x * QTILE + wave * 32;
  const int jbase0 = blockIdx.y * (SEQ / NSPLIT);

  // Q A-fragments, resident: A[m=lane&15][k=quad*8+j+32c], 2 row-sets
  f16x8 qf[2][4];
#pragma unroll
  for (int rs = 0; rs < 2; rs++)
#pragma unroll
    for (int c = 0; c < 4; c++)
      qf[rs][c] = *(const f16x8*)&Wh16[(size_t)(qbase + rs * 16 + n16) * DIM +
                                       c * 32 + quad * 8];

  floatx4 o[2][8];
#pragma unroll
  for (int rs = 0; rs < 2; rs++)
#pragma unroll
    for (int ct = 0; ct < 8; ct++) o[rs][ct] = (floatx4){0.f, 0.f, 0.f, 0.f};
  float m_run[2][4], l_run[2][4];
#pragma unroll
  for (int rs = 0; rs < 2; rs++)
#pragma unroll
    for (int e = 0; e < 4; e++) { m_run[rs][e] = -1e30f; l_run[rs][e] = 0.f; }

  for (int it = 0; it < JITER; it++) {
    const int jbase = jbase0 + it * BN;

    // ---- stage K/V tiles in fragment order: 32 chunks of 1 KB, 8 per wave.
    // K chunk q=t*4+c holds kf(t,c); V chunk q=ct*2+c holds vf(ct,c);
    // lane l's 16 B land at chunkbase + l*16 (HW scatter).
#pragma unroll
    for (int i = 0; i < 8; i++) {
      int ci = wave * 8 + i;                 // 0..31, wave-uniform branch
      if (ci < 16) {
        int t = ci >> 2, c = ci & 3;
        load_lds16(&Wh16[(size_t)(jbase + t * 16 + n16) * DIM + c * 32 + quad * 8],
                   &Kbuf[ci * 512]);
      } else {
        int q = ci - 16, ct = q >> 1, c = q & 1;
        load_lds16(&WhT16[(size_t)(ct * 16 + n16) * SEQ + jbase + c * 32 + quad * 8],
                   &Vbuf[q * 512]);
      }
    }
    __syncthreads();   // vmcnt(0) drain: staging complete

    // ---- S = Q K^T : linear conflict-free frag reads, each feeds 2 MFMAs
    floatx4 s[2][4];
#pragma unroll
    for (int rs = 0; rs < 2; rs++)
#pragma unroll
      for (int t = 0; t < 4; t++) s[rs][t] = (floatx4){0.f, 0.f, 0.f, 0.f};
#pragma unroll
    for (int t = 0; t < 4; t++)
#pragma unroll
      for (int c = 0; c < 4; c++) {
        f16x8 kf = *(const f16x8*)&Kbuf[(t * 4 + c) * 512 + lane * 8];
        s[0][t] = __builtin_amdgcn_mfma_f32_16x16x32_f16(qf[0][c], kf, s[0][t], 0, 0, 0);
        s[1][t] = __builtin_amdgcn_mfma_f32_16x16x32_f16(qf[1][c], kf, s[1][t], 0, 0, 0);
      }

    // ---- leaky_relu + online softmax (R1-verbatim, per row-set)
    f16x8 pa[2][2];
#pragma unroll
    for (int rs = 0; rs < 2; rs++) {
#pragma unroll
      for (int t = 0; t < 4; t++)
#pragma unroll
        for (int e = 0; e < 4; e++) {
          float v = s[rs][t][e];
          s[rs][t][e] = v > 0.f ? v : 0.2f * v;
        }
      float alpha[4];
#pragma unroll
      for (int e = 0; e < 4; e++) {
        float v = fmaxf(fmaxf(s[rs][0][e], s[rs][1][e]),
                        fmaxf(s[rs][2][e], s[rs][3][e]));
        v = fmaxf(v, __shfl_xor(v, 1, 64));
        v = fmaxf(v, __shfl_xor(v, 2, 64));
        v = fmaxf(v, __shfl_xor(v, 4, 64));
        v = fmaxf(v, __shfl_xor(v, 8, 64));
        float mnew = fmaxf(m_run[rs][e], v);
        alpha[e] = __expf(m_run[rs][e] - mnew);
        m_run[rs][e] = mnew;
      }
      float rsum[4] = {0.f, 0.f, 0.f, 0.f};
#pragma unroll
      for (int t = 0; t < 4; t++)
#pragma unroll
        for (int e = 0; e < 4; e++) {
          float p = __expf(s[rs][t][e] - m_run[rs][e]);
          s[rs][t][e] = p;
          rsum[e] += p;
        }
#pragma unroll
      for (int e = 0; e < 4; e++) {
        float v = rsum[e];
        v += __shfl_xor(v, 1, 64);
        v += __shfl_xor(v, 2, 64);
        v += __shfl_xor(v, 4, 64);
        v += __shfl_xor(v, 8, 64);
        l_run[rs][e] = alpha[e] * l_run[rs][e] + v;
      }
#pragma unroll
      for (int ct = 0; ct < 8; ct++)
#pragma unroll
        for (int e = 0; e < 4; e++) o[rs][ct][e] *= alpha[e];

      // ---- P: C-layout -> A-layout via per-wave LDS region (intra-wave)
      _Float16* Pw = Psh + (wave * 2 + rs) * 1152;   // 16 rows x 72 halves
#pragma unroll
      for (int t = 0; t < 4; t++)
#pragma unroll
        for (int e = 0; e < 4; e++)
          Pw[(quad * 4 + e) * 72 + t * 16 + n16] = (_Float16)s[rs][t][e];
      asm volatile("s_waitcnt lgkmcnt(0)" ::: "memory");
#pragma unroll
      for (int c = 0; c < 2; c++)
        pa[rs][c] = *(const f16x8*)&Pw[n16 * 72 + c * 32 + quad * 8];
    }

    // ---- O += P V : linear conflict-free vf reads, each feeds 2 MFMAs
#pragma unroll
    for (int ct = 0; ct < 8; ct++)
#pragma unroll
      for (int c = 0; c < 2; c++) {
        f16x8 vf = *(const f16x8*)&Vbuf[(ct * 2 + c) * 512 + lane * 8];
        o[0][ct] = __builtin_amdgcn_mfma_f32_16x16x32_f16(pa[0][c], vf, o[0][ct], 0, 0, 0);
        o[1][ct] = __builtin_amdgcn_mfma_f32_16x16x32_f16(pa[1][c], vf, o[1][ct], 0, 0, 0);
      }
    __syncthreads();   // all frag reads done before next iter's staging
  }

  // ---- write unnormalized partials for this key-split (R1 pattern x2)
  const int sp = blockIdx.y;
  float* Op = Opart + (size_t)sp * SEQ * DIM;
#pragma unroll
  for (int rs = 0; rs < 2; rs++)
#pragma unroll
    for (int ct = 0; ct < 8; ct++)
#pragma unroll
      for (int e = 0; e < 4; e++) {
        int row = qbase + rs * 16 + quad * 4 + e;
        Op[(size_t)row * DIM + ct * 16 + n16] = o[rs][ct][e];
      }
  if (n16 == 0) {
#pragma unroll
    for (int rs = 0; rs < 2; rs++)
#pragma unroll
      for (int e = 0; e < 4; e++) {
        int row = qbase + rs * 16 + quad * 4 + e;
        mpart[sp * SEQ + row] = m_run[rs][e];
        lpart[sp * SEQ + row] = l_run[rs][e];
      }
  }
}

// ---------------------------------------------------------------------------
// Kernel 3: log-sum-exp combine of NSPLIT partials -> out fp32 (R1 verbatim)
// ---------------------------------------------------------------------------
__global__ __launch_bounds__(256) void combine_kernel(
    const float* __restrict__ Opart, const float* __restrict__ mpart,
    const float* __restrict__ lpart, float* __restrict__ out) {
  int idx = blockIdx.x * 256 + threadIdx.x;
  int row = idx >> 7;
  float M = -1e30f;
#pragma unroll
  for (int p = 0; p < NSPLIT; p++) M = fmaxf(M, mpart[p * SEQ + row]);
  float num = 0.f, den = 0.f;
#pragma unroll
  for (int p = 0; p < NSPLIT; p++) {
    float e = __expf(mpart[p * SEQ + row] - M);
    den += e * lpart[p * SEQ + row];
    num += e * Opart[(size_t)p * SEQ * DIM + idx];
  }
  out[idx] = num / den;
}

// ---------------------------------------------------------------------------
extern "C" void kernel_launch(void* const* d_in, const int* in_sizes, int n_in,
                              void* d_out, int out_size, void* d_ws,
                              size_t ws_size, hipStream_t stream) {
  const float* h = (const float*)d_in[0];
  // d_in[1] = adj (unused by the reference math)
  const float* W = (const float*)d_in[2];
  float* out = (float*)d_out;

  char* ws = (char*)d_ws;
  _Float16* Wh16  = (_Float16*)ws;                                   // 2 MiB
  _Float16* WhT16 = (_Float16*)(ws + (size_t)2 * 1024 * 1024);       // 2 MiB
  float* Opart = (float*)(ws + (size_t)4 * 1024 * 1024);             // 32 MiB
  float* mpart = (float*)(ws + (size_t)36 * 1024 * 1024);            // 256 KiB
  float* lpart = (float*)(ws + (size_t)36 * 1024 * 1024 + 256 * 1024);

  wh_kernel<<<SEQ / 8, 256, 0, stream>>>(h, W, Wh16, WhT16);
  flash_kernel<<<dim3(SEQ / QTILE, NSPLIT), 256, 0, stream>>>(Wh16, WhT16,
                                                              Opart, mpart, lpart);
  combine_kernel<<<(SEQ * DIM) / 256, 256, 0, stream>>>(Opart, mpart, lpart, out);
}

// Round 5
// 456.217 us; speedup vs baseline: 1.3136x; 1.0436x over previous
//
#include <hip/hip_runtime.h>
#include <hip/hip_bf16.h>

// GAT self-attention: Wh = h@W; out = softmax(leaky_relu(Wh@Wh^T)) @ Wh
// N=8192, IN_F=256, OUT_F=128. adj unused.
//
// Round 5 = Round 4 with ONE change: QK^T computed transposed (S^T = K Q^T,
// just swapped MFMA operands). S^T's C-layout puts each lane's 16 values on
// its OWN query row (col=lane&15=qrow), so softmax max/sum are in-register
// trees + shfl_xor(16,32) only: cross-lane ops drop 72 -> 16 per wave-iter.
// Staging (global_load_lds width=16, fragment order), P LDS buffer, PV,
// epilogue, wh/combine: R4-verbatim.

#define SEQ   8192
#define DIM   128
#define IN_F  256
#define BN    64
#define QTILE 128
#define NSPLIT 8
#define JITER ((SEQ / NSPLIT) / BN)   // 16

typedef __attribute__((ext_vector_type(8))) _Float16 f16x8;
typedef __attribute__((ext_vector_type(4))) _Float16 f16x4;
typedef __attribute__((ext_vector_type(4))) float   floatx4;

__device__ __forceinline__ void load_lds16(const void* g, void* l) {
  __builtin_amdgcn_global_load_lds(
      (const __attribute__((address_space(1))) unsigned int*)g,
      (__attribute__((address_space(3))) unsigned int*)l, 16, 0, 0);
}

// ---------------------------------------------------------------------------
// Kernel 1: Wh = h @ W (fp32 accum), emit Wh (f16 row-major) and Wh^T (f16).
// ---------------------------------------------------------------------------
__global__ __launch_bounds__(256) void wh_kernel(
    const float* __restrict__ h, const float* __restrict__ W,
    _Float16* __restrict__ Wh16, _Float16* __restrict__ WhT16) {
  int tid = threadIdx.x;
  int cg  = tid & 31;
  int rl  = tid >> 5;
  int row = blockIdx.x * 8 + rl;
  const float4* W4 = (const float4*)W;
  const float4* h4 = (const float4*)(h + (size_t)row * IN_F);
  float4 acc = make_float4(0.f, 0.f, 0.f, 0.f);
#pragma unroll 8
  for (int k4 = 0; k4 < IN_F / 4; k4++) {
    float4 hv = h4[k4];
    float4 w0 = W4[(k4 * 4 + 0) * 32 + cg];
    float4 w1 = W4[(k4 * 4 + 1) * 32 + cg];
    float4 w2 = W4[(k4 * 4 + 2) * 32 + cg];
    float4 w3 = W4[(k4 * 4 + 3) * 32 + cg];
    acc.x += hv.x * w0.x + hv.y * w1.x + hv.z * w2.x + hv.w * w3.x;
    acc.y += hv.x * w0.y + hv.y * w1.y + hv.z * w2.y + hv.w * w3.y;
    acc.z += hv.x * w0.z + hv.y * w1.z + hv.z * w2.z + hv.w * w3.z;
    acc.w += hv.x * w0.w + hv.y * w1.w + hv.z * w2.w + hv.w * w3.w;
  }
  f16x4 r;
  r[0] = (_Float16)acc.x; r[1] = (_Float16)acc.y;
  r[2] = (_Float16)acc.z; r[3] = (_Float16)acc.w;
  *(f16x4*)&Wh16[(size_t)row * DIM + cg * 4] = r;
#pragma unroll
  for (int j = 0; j < 4; j++)
    WhT16[(size_t)(cg * 4 + j) * SEQ + row] = r[j];
}

// ---------------------------------------------------------------------------
// Kernel 2: flash attention, LDS-staged in fragment order, S^T softmax.
// grid (SEQ/QTILE=64, NSPLIT=8), block 256 = 4 waves; wave owns 32 Q rows.
// ---------------------------------------------------------------------------
__global__ __launch_bounds__(256) void flash_kernel(
    const _Float16* __restrict__ Wh16, const _Float16* __restrict__ WhT16,
    float* __restrict__ Opart, float* __restrict__ mpart,
    float* __restrict__ lpart) {
  __shared__ _Float16 Kbuf[16 * 512];       // 16 KiB
  __shared__ _Float16 Vbuf[16 * 512];       // 16 KiB
  __shared__ _Float16 Psh[4 * 2 * 16 * 72]; // 18 KiB

  const int tid  = threadIdx.x;
  const int lane = tid & 63;
  const int wave = tid >> 6;
  const int n16  = lane & 15;
  const int quad = lane >> 4;

  const int qbase  = blockIdx.x * QTILE + wave * 32;
  const int jbase0 = blockIdx.y * (SEQ / NSPLIT);

  // Q fragments (used as B-operand now): [n=qrow=lane&15][k=quad*8+j+32c]
  f16x8 qf[2][4];
#pragma unroll
  for (int rs = 0; rs < 2; rs++)
#pragma unroll
    for (int c = 0; c < 4; c++)
      qf[rs][c] = *(const f16x8*)&Wh16[(size_t)(qbase + rs * 16 + n16) * DIM +
                                       c * 32 + quad * 8];

  floatx4 o[2][8];
#pragma unroll
  for (int rs = 0; rs < 2; rs++)
#pragma unroll
    for (int ct = 0; ct < 8; ct++) o[rs][ct] = (floatx4){0.f, 0.f, 0.f, 0.f};
  // running max / sum for query row n16 (per-lane; quads hold copies)
  float m_run[2] = {-1e30f, -1e30f};
  float l_run[2] = {0.f, 0.f};

  for (int it = 0; it < JITER; it++) {
    const int jbase = jbase0 + it * BN;

    // ---- stage K/V tiles in fragment order: 32 chunks of 1 KB, 8 per wave.
#pragma unroll
    for (int i = 0; i < 8; i++) {
      int ci = wave * 8 + i;                 // 0..31, wave-uniform
      if (ci < 16) {
        int t = ci >> 2, c = ci & 3;
        load_lds16(&Wh16[(size_t)(jbase + t * 16 + n16) * DIM + c * 32 + quad * 8],
                   &Kbuf[ci * 512]);
      } else {
        int q = ci - 16, ct = q >> 1, c = q & 1;
        load_lds16(&WhT16[(size_t)(ct * 16 + n16) * SEQ + jbase + c * 32 + quad * 8],
                   &Vbuf[q * 512]);
      }
    }
    __syncthreads();

    // ---- S^T = K Q^T : A=kf, B=qf. C-layout: col=lane&15=qrow,
    //      row=quad*4+e = key within subtile t (key = t*16+quad*4+e).
    floatx4 st[2][4];
#pragma unroll
    for (int rs = 0; rs < 2; rs++)
#pragma unroll
      for (int t = 0; t < 4; t++) st[rs][t] = (floatx4){0.f, 0.f, 0.f, 0.f};
#pragma unroll
    for (int t = 0; t < 4; t++)
#pragma unroll
      for (int c = 0; c < 4; c++) {
        f16x8 kf = *(const f16x8*)&Kbuf[(t * 4 + c) * 512 + lane * 8];
        st[0][t] = __builtin_amdgcn_mfma_f32_16x16x32_f16(kf, qf[0][c], st[0][t], 0, 0, 0);
        st[1][t] = __builtin_amdgcn_mfma_f32_16x16x32_f16(kf, qf[1][c], st[1][t], 0, 0, 0);
      }

    // ---- leaky_relu + online softmax on own-row values + P write
    f16x8 pa[2][2];
#pragma unroll
    for (int rs = 0; rs < 2; rs++) {
#pragma unroll
      for (int t = 0; t < 4; t++)
#pragma unroll
        for (int e = 0; e < 4; e++) {
          float v = st[rs][t][e];
          st[rs][t][e] = v > 0.f ? v : 0.2f * v;
        }
      // row max: in-register over 16 + shfl_xor(16,32)
      float mloc = st[rs][0][0];
#pragma unroll
      for (int t = 0; t < 4; t++)
#pragma unroll
        for (int e = 0; e < 4; e++) mloc = fmaxf(mloc, st[rs][t][e]);
      mloc = fmaxf(mloc, __shfl_xor(mloc, 16, 64));
      mloc = fmaxf(mloc, __shfl_xor(mloc, 32, 64));
      float mnew = fmaxf(m_run[rs], mloc);
      float alpha = __expf(m_run[rs] - mnew);
      m_run[rs] = mnew;
      // exp + row sum + P^T write into [qrow][key] buffer
      _Float16* Pw = Psh + (wave * 2 + rs) * 1152;   // 16 rows x 72 halves
      float sum = 0.f;
#pragma unroll
      for (int t = 0; t < 4; t++)
#pragma unroll
        for (int e = 0; e < 4; e++) {
          float p = __expf(st[rs][t][e] - mnew);
          sum += p;
          Pw[n16 * 72 + t * 16 + quad * 4 + e] = (_Float16)p;
        }
      sum += __shfl_xor(sum, 16, 64);
      sum += __shfl_xor(sum, 32, 64);
      l_run[rs] = alpha * l_run[rs] + sum;
      // rescale O (C-layout rows quad*4+e): alpha for row r is in lane r
#pragma unroll
      for (int e = 0; e < 4; e++) {
        float ae = __shfl(alpha, quad * 4 + e, 64);
#pragma unroll
        for (int ct = 0; ct < 8; ct++) o[rs][ct][e] *= ae;
      }
      asm volatile("s_waitcnt lgkmcnt(0)" ::: "memory");
#pragma unroll
      for (int c = 0; c < 2; c++)
        pa[rs][c] = *(const f16x8*)&Pw[n16 * 72 + c * 32 + quad * 8];
    }

    // ---- O += P V : linear conflict-free vf reads, each feeds 2 MFMAs
#pragma unroll
    for (int ct = 0; ct < 8; ct++)
#pragma unroll
      for (int c = 0; c < 2; c++) {
        f16x8 vf = *(const f16x8*)&Vbuf[(ct * 2 + c) * 512 + lane * 8];
        o[0][ct] = __builtin_amdgcn_mfma_f32_16x16x32_f16(pa[0][c], vf, o[0][ct], 0, 0, 0);
        o[1][ct] = __builtin_amdgcn_mfma_f32_16x16x32_f16(pa[1][c], vf, o[1][ct], 0, 0, 0);
      }
    __syncthreads();
  }

  // ---- write unnormalized partials for this key-split
  const int sp = blockIdx.y;
  float* Op = Opart + (size_t)sp * SEQ * DIM;
#pragma unroll
  for (int rs = 0; rs < 2; rs++)
#pragma unroll
    for (int ct = 0; ct < 8; ct++)
#pragma unroll
      for (int e = 0; e < 4; e++) {
        int row = qbase + rs * 16 + quad * 4 + e;
        Op[(size_t)row * DIM + ct * 16 + n16] = o[rs][ct][e];
      }
  if (quad == 0) {   // lane holds m/l for query row n16
#pragma unroll
    for (int rs = 0; rs < 2; rs++) {
      int row = qbase + rs * 16 + n16;
      mpart[sp * SEQ + row] = m_run[rs];
      lpart[sp * SEQ + row] = l_run[rs];
    }
  }
}

// ---------------------------------------------------------------------------
// Kernel 3: log-sum-exp combine of NSPLIT partials -> out fp32
// ---------------------------------------------------------------------------
__global__ __launch_bounds__(256) void combine_kernel(
    const float* __restrict__ Opart, const float* __restrict__ mpart,
    const float* __restrict__ lpart, float* __restrict__ out) {
  int idx = blockIdx.x * 256 + threadIdx.x;
  int row = idx >> 7;
  float M = -1e30f;
#pragma unroll
  for (int p = 0; p < NSPLIT; p++) M = fmaxf(M, mpart[p * SEQ + row]);
  float num = 0.f, den = 0.f;
#pragma unroll
  for (int p = 0; p < NSPLIT; p++) {
    float e = __expf(mpart[p * SEQ + row] - M);
    den += e * lpart[p * SEQ + row];
    num += e * Opart[(size_t)p * SEQ * DIM + idx];
  }
  out[idx] = num / den;
}

// ---------------------------------------------------------------------------
extern "C" void kernel_launch(void* const* d_in, const int* in_sizes, int n_in,
                              void* d_out, int out_size, void* d_ws,
                              size_t ws_size, hipStream_t stream) {
  const float* h = (const float*)d_in[0];
  // d_in[1] = adj (unused by the reference math)
  const float* W = (const float*)d_in[2];
  float* out = (float*)d_out;

  char* ws = (char*)d_ws;
  _Float16* Wh16  = (_Float16*)ws;                                   // 2 MiB
  _Float16* WhT16 = (_Float16*)(ws + (size_t)2 * 1024 * 1024);       // 2 MiB
  float* Opart = (float*)(ws + (size_t)4 * 1024 * 1024);             // 32 MiB
  float* mpart = (float*)(ws + (size_t)36 * 1024 * 1024);            // 256 KiB
  float* lpart = (float*)(ws + (size_t)36 * 1024 * 1024 + 256 * 1024);

  wh_kernel<<<SEQ / 8, 256, 0, stream>>>(h, W, Wh16, WhT16);
  flash_kernel<<<dim3(SEQ / QTILE, NSPLIT), 256, 0, stream>>>(Wh16, WhT16,
                                                              Opart, mpart, lpart);
  combine_kernel<<<(SEQ * DIM) / 256, 256, 0, stream>>>(Opart, mpart, lpart, out);
}

// Round 6
// 453.264 us; speedup vs baseline: 1.3221x; 1.0065x over previous
//
#include <hip/hip_runtime.h>
#include <hip/hip_bf16.h>

// GAT self-attention: Wh = h@W; out = softmax(leaky_relu(Wh@Wh^T)) @ Wh
// N=8192, IN_F=256, OUT_F=128. adj unused.
//
// Round 6 = Round 5 with ONE concept: the PV product is also transposed
// (O^T = V^T P^T, A=vf B=pa — same LDS reads, swapped MFMA operands). O^T's
// C-layout has col=lane&15=qrow, so every accumulator a lane holds is for
// its OWN query row: the 8 per-iter alpha-broadcast shfls are deleted, and
// P writes become 8 ds_write_b64 (4 consecutive keys per reg-quad) instead
// of 32 scalar writes. Staging / S^T / softmax reductions / combine are
// R5-verbatim. Epilogue re-indexed for the transposed accumulator.

#define SEQ   8192
#define DIM   128
#define IN_F  256
#define BN    64
#define QTILE 128
#define NSPLIT 8
#define JITER ((SEQ / NSPLIT) / BN)   // 16

typedef __attribute__((ext_vector_type(8))) _Float16 f16x8;
typedef __attribute__((ext_vector_type(4))) _Float16 f16x4;
typedef __attribute__((ext_vector_type(4))) float   floatx4;

__device__ __forceinline__ void load_lds16(const void* g, void* l) {
  __builtin_amdgcn_global_load_lds(
      (const __attribute__((address_space(1))) unsigned int*)g,
      (__attribute__((address_space(3))) unsigned int*)l, 16, 0, 0);
}

// ---------------------------------------------------------------------------
// Kernel 1: Wh = h @ W (fp32 accum), emit Wh (f16 row-major) and Wh^T (f16).
// ---------------------------------------------------------------------------
__global__ __launch_bounds__(256) void wh_kernel(
    const float* __restrict__ h, const float* __restrict__ W,
    _Float16* __restrict__ Wh16, _Float16* __restrict__ WhT16) {
  int tid = threadIdx.x;
  int cg  = tid & 31;
  int rl  = tid >> 5;
  int row = blockIdx.x * 8 + rl;
  const float4* W4 = (const float4*)W;
  const float4* h4 = (const float4*)(h + (size_t)row * IN_F);
  float4 acc = make_float4(0.f, 0.f, 0.f, 0.f);
#pragma unroll 8
  for (int k4 = 0; k4 < IN_F / 4; k4++) {
    float4 hv = h4[k4];
    float4 w0 = W4[(k4 * 4 + 0) * 32 + cg];
    float4 w1 = W4[(k4 * 4 + 1) * 32 + cg];
    float4 w2 = W4[(k4 * 4 + 2) * 32 + cg];
    float4 w3 = W4[(k4 * 4 + 3) * 32 + cg];
    acc.x += hv.x * w0.x + hv.y * w1.x + hv.z * w2.x + hv.w * w3.x;
    acc.y += hv.x * w0.y + hv.y * w1.y + hv.z * w2.y + hv.w * w3.y;
    acc.z += hv.x * w0.z + hv.y * w1.z + hv.z * w2.z + hv.w * w3.z;
    acc.w += hv.x * w0.w + hv.y * w1.w + hv.z * w2.w + hv.w * w3.w;
  }
  f16x4 r;
  r[0] = (_Float16)acc.x; r[1] = (_Float16)acc.y;
  r[2] = (_Float16)acc.z; r[3] = (_Float16)acc.w;
  *(f16x4*)&Wh16[(size_t)row * DIM + cg * 4] = r;
#pragma unroll
  for (int j = 0; j < 4; j++)
    WhT16[(size_t)(cg * 4 + j) * SEQ + row] = r[j];
}

// ---------------------------------------------------------------------------
// Kernel 2: flash attention, fully-transposed (S^T and O^T), LDS-staged in
// fragment order. grid (SEQ/QTILE=64, NSPLIT=8), block 256 = 4 waves;
// wave owns 32 Q rows (2 row-sets of 16).
// ---------------------------------------------------------------------------
__global__ __launch_bounds__(256) void flash_kernel(
    const _Float16* __restrict__ Wh16, const _Float16* __restrict__ WhT16,
    float* __restrict__ Opart, float* __restrict__ mpart,
    float* __restrict__ lpart) {
  __shared__ _Float16 Kbuf[16 * 512];       // 16 KiB
  __shared__ _Float16 Vbuf[16 * 512];       // 16 KiB
  __shared__ _Float16 Psh[4 * 2 * 16 * 72]; // 18 KiB

  const int tid  = threadIdx.x;
  const int lane = tid & 63;
  const int wave = tid >> 6;
  const int n16  = lane & 15;
  const int quad = lane >> 4;

  const int qbase  = blockIdx.x * QTILE + wave * 32;
  const int jbase0 = blockIdx.y * (SEQ / NSPLIT);

  // Q fragments (B-operand of S^T): [n=qrow=lane&15][k=quad*8+j+32c]
  f16x8 qf[2][4];
#pragma unroll
  for (int rs = 0; rs < 2; rs++)
#pragma unroll
    for (int c = 0; c < 4; c++)
      qf[rs][c] = *(const f16x8*)&Wh16[(size_t)(qbase + rs * 16 + n16) * DIM +
                                       c * 32 + quad * 8];

  // O^T accumulators: o[rs][dt] C-layout: col=lane&15 = qrow (own row!),
  // row = quad*4+e = dim within tile dt.
  floatx4 o[2][8];
#pragma unroll
  for (int rs = 0; rs < 2; rs++)
#pragma unroll
    for (int dt = 0; dt < 8; dt++) o[rs][dt] = (floatx4){0.f, 0.f, 0.f, 0.f};
  float m_run[2] = {-1e30f, -1e30f};
  float l_run[2] = {0.f, 0.f};

  for (int it = 0; it < JITER; it++) {
    const int jbase = jbase0 + it * BN;

    // ---- stage K/V tiles in fragment order: 32 chunks of 1 KB, 8 per wave.
#pragma unroll
    for (int i = 0; i < 8; i++) {
      int ci = wave * 8 + i;                 // 0..31, wave-uniform
      if (ci < 16) {
        int t = ci >> 2, c = ci & 3;
        load_lds16(&Wh16[(size_t)(jbase + t * 16 + n16) * DIM + c * 32 + quad * 8],
                   &Kbuf[ci * 512]);
      } else {
        int q = ci - 16, ct = q >> 1, c = q & 1;
        load_lds16(&WhT16[(size_t)(ct * 16 + n16) * SEQ + jbase + c * 32 + quad * 8],
                   &Vbuf[q * 512]);
      }
    }
    __syncthreads();

    // ---- S^T = K Q^T : col=lane&15=qrow, row=key=t*16+quad*4+e
    floatx4 st[2][4];
#pragma unroll
    for (int rs = 0; rs < 2; rs++)
#pragma unroll
      for (int t = 0; t < 4; t++) st[rs][t] = (floatx4){0.f, 0.f, 0.f, 0.f};
#pragma unroll
    for (int t = 0; t < 4; t++)
#pragma unroll
      for (int c = 0; c < 4; c++) {
        f16x8 kf = *(const f16x8*)&Kbuf[(t * 4 + c) * 512 + lane * 8];
        st[0][t] = __builtin_amdgcn_mfma_f32_16x16x32_f16(kf, qf[0][c], st[0][t], 0, 0, 0);
        st[1][t] = __builtin_amdgcn_mfma_f32_16x16x32_f16(kf, qf[1][c], st[1][t], 0, 0, 0);
      }

    // ---- leaky_relu + online softmax on own-row values + vectorized P write
    f16x8 pa[2][2];
    float alpha[2];
#pragma unroll
    for (int rs = 0; rs < 2; rs++) {
#pragma unroll
      for (int t = 0; t < 4; t++)
#pragma unroll
        for (int e = 0; e < 4; e++) {
          float v = st[rs][t][e];
          st[rs][t][e] = v > 0.f ? v : 0.2f * v;
        }
      float mloc = st[rs][0][0];
#pragma unroll
      for (int t = 0; t < 4; t++)
#pragma unroll
        for (int e = 0; e < 4; e++) mloc = fmaxf(mloc, st[rs][t][e]);
      mloc = fmaxf(mloc, __shfl_xor(mloc, 16, 64));
      mloc = fmaxf(mloc, __shfl_xor(mloc, 32, 64));
      float mnew = fmaxf(m_run[rs], mloc);
      alpha[rs] = __expf(m_run[rs] - mnew);
      m_run[rs] = mnew;
      _Float16* Pw = Psh + (wave * 2 + rs) * 1152;   // 16 rows x 72 halves
      float sum = 0.f;
#pragma unroll
      for (int t = 0; t < 4; t++) {
        f16x4 pk;
#pragma unroll
        for (int e = 0; e < 4; e++) {
          float p = __expf(st[rs][t][e] - mnew);
          sum += p;
          pk[e] = (_Float16)p;
        }
        // keys t*16+quad*4 .. +3 of row n16: one b64 write
        *(f16x4*)&Pw[n16 * 72 + t * 16 + quad * 4] = pk;
      }
      sum += __shfl_xor(sum, 16, 64);
      sum += __shfl_xor(sum, 32, 64);
      l_run[rs] = alpha[rs] * l_run[rs] + sum;
      // rescale O^T: every value this lane holds is for qrow n16 -> own alpha
#pragma unroll
      for (int dt = 0; dt < 8; dt++)
#pragma unroll
        for (int e = 0; e < 4; e++) o[rs][dt][e] *= alpha[rs];
      asm volatile("s_waitcnt lgkmcnt(0)" ::: "memory");
      // pa = P^T B-frags: B[k=key=quad*8+j+32c][n=qrow=lane&15]
#pragma unroll
      for (int c = 0; c < 2; c++)
        pa[rs][c] = *(const f16x8*)&Pw[n16 * 72 + c * 32 + quad * 8];
    }

    // ---- O^T += V^T P^T : A=vf (same reads as before), B=pa
#pragma unroll
    for (int dt = 0; dt < 8; dt++)
#pragma unroll
      for (int c = 0; c < 2; c++) {
        f16x8 vf = *(const f16x8*)&Vbuf[(dt * 2 + c) * 512 + lane * 8];
        o[0][dt] = __builtin_amdgcn_mfma_f32_16x16x32_f16(vf, pa[0][c], o[0][dt], 0, 0, 0);
        o[1][dt] = __builtin_amdgcn_mfma_f32_16x16x32_f16(vf, pa[1][c], o[1][dt], 0, 0, 0);
      }
    __syncthreads();
  }

  // ---- write unnormalized partials (O^T layout: row=qbase+rs*16+n16,
  //      dim = dt*16 + quad*4 + e)
  const int sp = blockIdx.y;
  float* Op = Opart + (size_t)sp * SEQ * DIM;
#pragma unroll
  for (int rs = 0; rs < 2; rs++) {
    int row = qbase + rs * 16 + n16;
#pragma unroll
    for (int dt = 0; dt < 8; dt++)
#pragma unroll
      for (int e = 0; e < 4; e++)
        Op[(size_t)row * DIM + dt * 16 + quad * 4 + e] = o[rs][dt][e];
  }
  if (quad == 0) {   // lane holds m/l for query row n16
#pragma unroll
    for (int rs = 0; rs < 2; rs++) {
      int row = qbase + rs * 16 + n16;
      mpart[sp * SEQ + row] = m_run[rs];
      lpart[sp * SEQ + row] = l_run[rs];
    }
  }
}

// ---------------------------------------------------------------------------
// Kernel 3: log-sum-exp combine of NSPLIT partials -> out fp32
// ---------------------------------------------------------------------------
__global__ __launch_bounds__(256) void combine_kernel(
    const float* __restrict__ Opart, const float* __restrict__ mpart,
    const float* __restrict__ lpart, float* __restrict__ out) {
  int idx = blockIdx.x * 256 + threadIdx.x;
  int row = idx >> 7;
  float M = -1e30f;
#pragma unroll
  for (int p = 0; p < NSPLIT; p++) M = fmaxf(M, mpart[p * SEQ + row]);
  float num = 0.f, den = 0.f;
#pragma unroll
  for (int p = 0; p < NSPLIT; p++) {
    float e = __expf(mpart[p * SEQ + row] - M);
    den += e * lpart[p * SEQ + row];
    num += e * Opart[(size_t)p * SEQ * DIM + idx];
  }
  out[idx] = num / den;
}

// ---------------------------------------------------------------------------
extern "C" void kernel_launch(void* const* d_in, const int* in_sizes, int n_in,
                              void* d_out, int out_size, void* d_ws,
                              size_t ws_size, hipStream_t stream) {
  const float* h = (const float*)d_in[0];
  // d_in[1] = adj (unused by the reference math)
  const float* W = (const float*)d_in[2];
  float* out = (float*)d_out;

  char* ws = (char*)d_ws;
  _Float16* Wh16  = (_Float16*)ws;                                   // 2 MiB
  _Float16* WhT16 = (_Float16*)(ws + (size_t)2 * 1024 * 1024);       // 2 MiB
  float* Opart = (float*)(ws + (size_t)4 * 1024 * 1024);             // 32 MiB
  float* mpart = (float*)(ws + (size_t)36 * 1024 * 1024);            // 256 KiB
  float* lpart = (float*)(ws + (size_t)36 * 1024 * 1024 + 256 * 1024);

  wh_kernel<<<SEQ / 8, 256, 0, stream>>>(h, W, Wh16, WhT16);
  flash_kernel<<<dim3(SEQ / QTILE, NSPLIT), 256, 0, stream>>>(Wh16, WhT16,
                                                              Opart, mpart, lpart);
  combine_kernel<<<(SEQ * DIM) / 256, 256, 0, stream>>>(Opart, mpart, lpart, out);
}